// Round 1
// baseline (8581.754 us; speedup 1.0000x reference)
//
#include <hip/hip_runtime.h>
#include <hip/hip_cooperative_groups.h>

namespace cg = cooperative_groups;

typedef short bf16x8 __attribute__((ext_vector_type(8)));
typedef float f32x4 __attribute__((ext_vector_type(4)));

// ---------- bf16 helpers (bit-exact RNE, no lib dependence) ----------
__device__ __forceinline__ short f2bf(float f) {
  union { float f; unsigned u; } v; v.f = f;
  unsigned r = v.u + 0x7FFFu + ((v.u >> 16) & 1u);
  return (short)(r >> 16);
}
__device__ __forceinline__ float bf2f(short s) {
  union { unsigned u; float f; } v; v.u = ((unsigned)(unsigned short)s) << 16;
  return v.f;
}

// ---------- async global->LDS, 16B per lane ----------
typedef __attribute__((address_space(1))) const void* gas_cvp;
typedef __attribute__((address_space(3))) void* las_vp;
__device__ __forceinline__ void async16(const void* g, void* s) {
  __builtin_amdgcn_global_load_lds((gas_cvp)g, (las_vp)s, 16, 0, 0);
}

// ---------- prep kernels ----------
__global__ void cast4_kernel(const float* __restrict__ src, short* __restrict__ dst, int n) {
  int i = (blockIdx.x * blockDim.x + threadIdx.x) * 4;
  int stride = gridDim.x * blockDim.x * 4;
  for (; i < n; i += stride) {
    float4 v = *(const float4*)(src + i);
    short4 o;
    o.x = f2bf(v.x); o.y = f2bf(v.y); o.z = f2bf(v.z); o.w = f2bf(v.w);
    *(short4*)(dst + i) = o;
  }
}

// X rows ordered (b*256 + t); token(b,0)=START=1, token(b,t)=gold[b][t-1]
__global__ void build_x_kernel(const float* __restrict__ emb, const int* __restrict__ gold,
                               short* __restrict__ X) {
  int row = blockIdx.x;            // 0..8191
  int b = row >> 8, t = row & 255;
  int tok = (t == 0) ? 1 : gold[b * 256 + t - 1];
  const float* s = emb + (long long)tok * 1024;
  short* d = X + (long long)row * 1024;
  for (int c = threadIdx.x; c < 1024; c += blockDim.x) d[c] = f2bf(s[c]);
}

__global__ void init_h_kernel(const float* __restrict__ enc, float* __restrict__ hF,
                              short* __restrict__ hHi, short* __restrict__ hLo) {
  int i = blockIdx.x * blockDim.x + threadIdx.x;
  if (i < 32 * 1024) {
    float v = enc[i];
    short hi = f2bf(v);
    hF[i] = v;
    hHi[i] = hi;
    hLo[i] = f2bf(v - bf2f(hi));
  }
}

// ---------- bf16 MFMA GEMM: C(M,N) = A(M,K) @ B(N,K)^T (+bias), fp32 out ----------
// 128x128 tile, BK=32, 256 threads (2x2 waves of 64x64), m97-style global_load_lds staging.
__global__ __launch_bounds__(256, 2) void gemm_bt(
    const short* __restrict__ A, const short* __restrict__ B,
    const float* __restrict__ bias, float* __restrict__ C,
    int M, int N, int K)
{
  __shared__ short As[128 * 32];
  __shared__ short Bs[128 * 32];
  const int tid = threadIdx.x;
  const int lane = tid & 63;
  const int wv = tid >> 6;
  const int m0 = blockIdx.y << 7, n0 = blockIdx.x << 7;
  const int wm = (wv >> 1) << 6, wn = (wv & 1) << 6;
  const int fr = lane & 15, fq = lane >> 4;

  f32x4 zero = {0.f, 0.f, 0.f, 0.f};
  f32x4 acc[4][4];
#pragma unroll
  for (int i = 0; i < 4; ++i)
#pragma unroll
    for (int j = 0; j < 4; ++j) acc[i][j] = zero;

  const int idx0 = tid, idx1 = tid + 256;
  const int ar0 = idx0 >> 2, ac0 = (idx0 & 3) << 3;
  const int ar1 = idx1 >> 2, ac1 = (idx1 & 3) << 3;
  const short* A0 = A + (long long)(m0 + ar0) * K + ac0;
  const short* A1 = A + (long long)(m0 + ar1) * K + ac1;
  const short* B0 = B + (long long)(n0 + ar0) * K + ac0;
  const short* B1 = B + (long long)(n0 + ar1) * K + ac1;

  for (int kb = 0; kb < K; kb += 32) {
    __syncthreads();
    async16(A0 + kb, &As[idx0 * 8]);
    async16(A1 + kb, &As[idx1 * 8]);
    async16(B0 + kb, &Bs[idx0 * 8]);
    async16(B1 + kb, &Bs[idx1 * 8]);
    asm volatile("s_waitcnt vmcnt(0)" ::: "memory");
    __syncthreads();
    bf16x8 af[4], bfr[4];
#pragma unroll
    for (int i = 0; i < 4; ++i)
      af[i] = *(const bf16x8*)&As[((wm + i * 16 + fr) << 5) + (fq << 3)];
#pragma unroll
    for (int j = 0; j < 4; ++j)
      bfr[j] = *(const bf16x8*)&Bs[((wn + j * 16 + fr) << 5) + (fq << 3)];
#pragma unroll
    for (int i = 0; i < 4; ++i)
#pragma unroll
      for (int j = 0; j < 4; ++j)
        acc[i][j] = __builtin_amdgcn_mfma_f32_16x16x32_bf16(af[i], bfr[j], acc[i][j], 0, 0, 0);
  }

  const int cr = fq << 2, cc = fr;
#pragma unroll
  for (int i = 0; i < 4; ++i) {
#pragma unroll
    for (int j = 0; j < 4; ++j) {
      int col = n0 + wn + j * 16 + cc;
      float bv = bias ? bias[col] : 0.f;
#pragma unroll
      for (int r = 0; r < 4; ++r) {
        int row = m0 + wm + i * 16 + cr + r;
        C[(long long)row * N + col] = acc[i][j][r] + bv;
      }
    }
  }
}

// ---------- persistent GRU recurrence (cooperative, 128 blocks x 256 threads) ----------
// Block owns 8 hidden units j; LDS holds its 24 w_hh rows as bf16 hi+lo (split precision).
// Per step: gh = h @ w_slice^T via 3-way split MFMA, gates in fp32, grid.sync().
__global__ __launch_bounds__(256, 1) void gru_rec(
    const float* __restrict__ w_hh, const float* __restrict__ b_hh,
    const float* __restrict__ GI,
    float* __restrict__ hF, short* __restrict__ hHi, short* __restrict__ hLo,
    short* __restrict__ Hall)
{
  __shared__ short ws_hi[32 * 1024];
  __shared__ short ws_lo[32 * 1024];
  __shared__ float gh_s[32 * 33];
  const int tid = threadIdx.x;
  const int blk = blockIdx.x;  // 0..127

  // stage weight slice: LDS row r = gate(r>>3)*8 + jl(r&7) -> w_hh[gate*1024 + blk*8 + jl]
  for (int idx = tid; idx < 24 * 1024; idx += 256) {
    int r = idx >> 10, k = idx & 1023;
    int g = r >> 3, jl = r & 7;
    float v = w_hh[(long long)((g << 10) + (blk << 3) + jl) * 1024 + k];
    short hi = f2bf(v);
    ws_hi[(r << 10) + k] = hi;
    ws_lo[(r << 10) + k] = f2bf(v - bf2f(hi));
  }
  for (int idx = tid; idx < 8 * 1024; idx += 256) {
    ws_hi[24 * 1024 + idx] = 0;
    ws_lo[24 * 1024 + idx] = 0;
  }

  // phase-2 mapping: thread -> (batch b2, local hidden jl2)
  const int b2 = tid >> 3, jl2 = tid & 7;
  const int jg = (blk << 3) + jl2;
  const float bhr = b_hh[jg], bhz = b_hh[1024 + jg], bhn = b_hh[2048 + jg];

  // phase-1 wave mapping: wave -> (mtile over batches, ntile over 16 gate-rows)
  const int lane = tid & 63, wv = tid >> 6;
  const int mt = wv & 1, nt = wv >> 1;
  const int aoff = (((mt << 4) + (lane & 15)) << 10) + ((lane >> 4) << 3);
  const int boff = (((nt << 4) + (lane & 15)) << 10) + ((lane >> 4) << 3);
  const int crow = (mt << 4) + ((lane >> 4) << 2);
  const int ccol = (nt << 4) + (lane & 15);

  __syncthreads();
  cg::grid_group grid = cg::this_grid();
  f32x4 zero = {0.f, 0.f, 0.f, 0.f};

  for (int t = 0; t < 256; ++t) {
    const int cur = t & 1, nxt = cur ^ 1;
    const short* hh = hHi + cur * 32768;
    const short* hl = hLo + cur * 32768;

    // prefetch phase-2 operands early (independent of phase-1)
    const long long girow = ((long long)(b2 << 8) + t) * 3072;
    float gir = GI[girow + jg];
    float giz = GI[girow + 1024 + jg];
    float gin = GI[girow + 2048 + jg];
    float hold = hF[cur * 32768 + (b2 << 10) + jg];

    // phase 1: gh = (h_hi+h_lo) @ (w_hi+w_lo)^T, drop lo*lo; 3 indep acc chains
    f32x4 a0 = zero, a1 = zero, a2 = zero;
#pragma unroll 8
    for (int kb = 0; kb < 32; ++kb) {
      bf16x8 ah = *(const bf16x8*)(hh + aoff + (kb << 5));
      bf16x8 al = *(const bf16x8*)(hl + aoff + (kb << 5));
      bf16x8 bh = *(const bf16x8*)(ws_hi + boff + (kb << 5));
      bf16x8 bl = *(const bf16x8*)(ws_lo + boff + (kb << 5));
      a0 = __builtin_amdgcn_mfma_f32_16x16x32_bf16(ah, bh, a0, 0, 0, 0);
      a1 = __builtin_amdgcn_mfma_f32_16x16x32_bf16(ah, bl, a1, 0, 0, 0);
      a2 = __builtin_amdgcn_mfma_f32_16x16x32_bf16(al, bh, a2, 0, 0, 0);
    }
#pragma unroll
    for (int r = 0; r < 4; ++r)
      gh_s[(crow + r) * 33 + ccol] = a0[r] + a1[r] + a2[r];
    __syncthreads();

    // phase 2: gates (fp32)
    {
      float ghr = gh_s[b2 * 33 + jl2] + bhr;
      float ghz = gh_s[b2 * 33 + 8 + jl2] + bhz;
      float ghn = gh_s[b2 * 33 + 16 + jl2] + bhn;
      float rg = 1.f / (1.f + __expf(-(gir + ghr)));
      float zg = 1.f / (1.f + __expf(-(giz + ghz)));
      float ng = tanhf(gin + rg * ghn);
      float hn = (1.f - zg) * ng + zg * hold;
      int hidx = (b2 << 10) + jg;
      hF[nxt * 32768 + hidx] = hn;
      short hi = f2bf(hn);
      hHi[nxt * 32768 + hidx] = hi;
      hLo[nxt * 32768 + hidx] = f2bf(hn - bf2f(hi));
      Hall[(long long)(((b2 << 8) + t) << 10) + jg] = hi;
    }
    grid.sync();
  }
}

// ---------- launch ----------
extern "C" void kernel_launch(void* const* d_in, const int* in_sizes, int n_in,
                              void* d_out, int out_size, void* d_ws, size_t ws_size,
                              hipStream_t stream) {
  (void)in_sizes; (void)n_in; (void)out_size; (void)ws_size;
  const float* enc  = (const float*)d_in[0];   // (1,32,1024)
  const float* emb  = (const float*)d_in[1];   // (32000,1024)
  const float* w_ih = (const float*)d_in[2];   // (3072,1024)
  const float* w_hh = (const float*)d_in[3];   // (3072,1024)
  const float* b_ih = (const float*)d_in[4];   // (3072,)
  const float* b_hh = (const float*)d_in[5];   // (3072,)
  const int*   gold = (const int*)d_in[6];     // (32,256)
  float* out = (float*)d_out;                  // (32,256,32000) fp32

  char* ws = (char*)d_ws;
  size_t off = 0;
  auto alloc = [&](size_t b) { char* p = ws + off; off += (b + 255) & ~(size_t)255; return p; };
  short* embB = (short*)alloc(32000ULL * 1024 * 2);  // emb bf16
  short* wihB = (short*)alloc(3072ULL * 1024 * 2);   // w_ih bf16
  short* X    = (short*)alloc(8192ULL * 1024 * 2);   // teacher-forced inputs bf16
  float* GI   = (float*)alloc(8192ULL * 3072 * 4);   // input-side gates fp32
  short* Hall = (short*)alloc(8192ULL * 1024 * 2);   // all h_t bf16, rows (b*256+t)
  float* hF   = (float*)alloc(2ULL * 32768 * 4);     // fp32 h ping-pong
  short* hHi  = (short*)alloc(2ULL * 32768 * 2);
  short* hLo  = (short*)alloc(2ULL * 32768 * 2);

  cast4_kernel<<<2048, 256, 0, stream>>>(emb, embB, 32000 * 1024);
  cast4_kernel<<<512, 256, 0, stream>>>(w_ih, wihB, 3072 * 1024);
  build_x_kernel<<<8192, 256, 0, stream>>>(emb, gold, X);
  init_h_kernel<<<128, 256, 0, stream>>>(enc, hF, hHi, hLo);

  // GI = X @ w_ih^T + b_ih   (M=8192, N=3072, K=1024)
  gemm_bt<<<dim3(24, 64), 256, 0, stream>>>(X, wihB, b_ih, GI, 8192, 3072, 1024);

  // serial GRU recurrence (cooperative)
  {
    void* args[] = {(void*)&w_hh, (void*)&b_hh, (void*)&GI,
                    (void*)&hF, (void*)&hHi, (void*)&hLo, (void*)&Hall};
    hipLaunchCooperativeKernel((void*)gru_rec, dim3(128), dim3(256), args, 0, stream);
  }

  // scores = Hall @ emb^T    (M=8192, N=32000, K=1024) -> d_out directly
  gemm_bt<<<dim3(250, 64), 256, 0, stream>>>(Hall, embB, nullptr, out, 8192, 32000, 1024);
}